// Round 6
// baseline (381.594 us; speedup 1.0000x reference)
//
#include <hip/hip_runtime.h>

#define B_ 4
#define T_ 2048
#define C_ 1024
#define H_ 4
#define D_ 256
#define M_ (B_*T_)      /* 8192 */
#define N1_ (4*C_)      /* 4096 */
#define K_ C_           /* 1024 */
#define LANES_ (B_*C_)  /* 4096 */
#define CHUNK_ 32
#define NCHUNK_ (T_/CHUNK_)  /* 64 */

typedef unsigned short u16;
typedef unsigned int u32;
typedef __bf16 bf16x8 __attribute__((ext_vector_type(8)));
typedef float f32x4 __attribute__((ext_vector_type(4)));
typedef float vf4 __attribute__((ext_vector_type(4)));
typedef unsigned short u16x4 __attribute__((ext_vector_type(4)));
typedef unsigned short u16x8 __attribute__((ext_vector_type(8)));

__device__ __forceinline__ u16 f2bf(float f) {
  union { float f; u32 u; } v; v.f = f;
  u32 u = v.u;
  u32 r = (u + 0x7FFFu + ((u >> 16) & 1u)) >> 16;
  return (u16)r;
}
__device__ __forceinline__ float b2f(u16 h) {
  union { u32 u; float f; } v; v.u = ((u32)h) << 16;
  return v.f;
}

#define NCAST_ ((N1_*K_ + C_*C_) / 2048)   /* 2560 blocks for weight cast */

// ---------------- merged prologue: weight casts + conv+SiLU + zero stats/flags ----------------
__global__ void prep_kernel(const float* __restrict__ wx_w, const float* __restrict__ out_w,
                            u16* __restrict__ w1p, u16* __restrict__ w2,
                            const float* __restrict__ x, const float* __restrict__ cw,
                            const float* __restrict__ cb, u16* __restrict__ xc,
                            float* __restrict__ stats, int* __restrict__ flags) {
  if (blockIdx.x < NCAST_) {
    int i8 = (blockIdx.x * 256 + threadIdx.x) * 8;
    u16x8 o;
    if (i8 < N1_ * K_) {
      int n = i8 >> 10, k8 = i8 & 1023;
      const float* src = wx_w + (size_t)(((n & 3) << 10) | (n >> 2)) * K_ + k8;
      vf4 a = *(const vf4*)src;
      vf4 b = *(const vf4*)(src + 4);
#pragma unroll
      for (int j = 0; j < 4; ++j) { o[j] = f2bf(a[j]); o[j + 4] = f2bf(b[j]); }
      *(u16x8*)(w1p + i8) = o;
    } else {
      int j8 = i8 - N1_ * K_;
      vf4 a = *(const vf4*)(out_w + j8);
      vf4 b = *(const vf4*)(out_w + j8 + 4);
#pragma unroll
      for (int j = 0; j < 4; ++j) { o[j] = f2bf(a[j]); o[j + 4] = f2bf(b[j]); }
      *(u16x8*)(w2 + j8) = o;
    }
    return;
  }
  if (blockIdx.x == NCAST_) {
    if (threadIdx.x < 32) stats[threadIdx.x] = 0.f;
    else if (threadIdx.x < 48) flags[threadIdx.x - 32] = 0;
  }
  int i4 = ((blockIdx.x - NCAST_) * 256 + threadIdx.x) * 4;
  int c = i4 & (C_ - 1);
  int t = (i4 >> 10) & (T_ - 1);
  vf4 acc = *(const vf4*)(cb + c);
  vf4 w0 = *(const vf4*)(cw + (size_t)c * 4);
  vf4 w1 = *(const vf4*)(cw + (size_t)(c + 1) * 4);
  vf4 w2v = *(const vf4*)(cw + (size_t)(c + 2) * 4);
  vf4 w3 = *(const vf4*)(cw + (size_t)(c + 3) * 4);
#pragma unroll
  for (int k = 0; k < 4; ++k) {
    if (t - 3 + k >= 0) {
      vf4 xv = *(const vf4*)(x + (size_t)i4 + (size_t)(k - 3) * C_);
      acc[0] = fmaf(w0[k], xv[0], acc[0]);
      acc[1] = fmaf(w1[k], xv[1], acc[1]);
      acc[2] = fmaf(w2v[k], xv[2], acc[2]);
      acc[3] = fmaf(w3[k], xv[3], acc[3]);
    }
  }
  u16x4 o;
#pragma unroll
  for (int j = 0; j < 4; ++j) {
    float s = acc[j] / (1.f + __expf(-acc[j]));
    o[j] = f2bf(s);
  }
  *(u16x4*)(xc + i4) = o;
}

// ---------------- bf16 MFMA GEMM, C[m][n] = sum_k A[m][k] * Bw[n][k] ----------------
template <int EPI>
__global__ __launch_bounds__(256, 3)
void gemm_bt(const u16* __restrict__ A, const u16* __restrict__ Bw,
             const float* __restrict__ bias, const float* __restrict__ resid,
             u16* __restrict__ obf, float* __restrict__ of32,
             f32x4* __restrict__ sSum, int M, int N, int K)
{
  __shared__ __align__(16) u16 smem[128 * 136];   // 34.8 KB; staging uses first 32 KB
  u16* a_s = smem;
  u16* b_s = smem + 128 * 64;

  const int tid  = threadIdx.x;
  const int lane = tid & 63;
  const int l15  = lane & 15;
  const int q    = lane >> 4;
  const int wave = tid >> 6;
  const int wm   = (wave >> 1) * 64;
  const int wn   = (wave & 1) * 64;
  const int bm   = blockIdx.y * 128;
  const int bn   = blockIdx.x * 128;

  const int srow   = wave * 8 + (lane >> 3);
  const int schunk = lane & 7;

  float bias4[4];
#pragma unroll
  for (int sn = 0; sn < 4; ++sn) {
    int gcol = bn + wn + sn * 16 + l15;
    bias4[sn] = (EPI == 0) ? bias[((gcol & 3) << 10) | (gcol >> 2)] : bias[gcol];
  }
  const bool zlane = (EPI == 0) && ((l15 & 3) == 2);

  f32x4 acc[4][4];
#pragma unroll
  for (int i = 0; i < 4; ++i)
#pragma unroll
    for (int j = 0; j < 4; ++j) acc[i][j] = (f32x4){0.f, 0.f, 0.f, 0.f};

  for (int k0 = 0; k0 < K; k0 += 64) {
#pragma unroll
    for (int i = 0; i < 4; ++i) {
      int r = i * 32 + srow;
      int lc = schunk ^ (r & 7);
      const u16* ga = A  + (size_t)(bm + r) * K + k0 + lc * 8;
      const u16* gb = Bw + (size_t)(bn + r) * K + k0 + lc * 8;
      __builtin_amdgcn_global_load_lds(
          (const __attribute__((address_space(1))) u32*)ga,
          (__attribute__((address_space(3))) u32*)&a_s[(i * 32 + wave * 8) * 64],
          16, 0, 0);
      __builtin_amdgcn_global_load_lds(
          (const __attribute__((address_space(1))) u32*)gb,
          (__attribute__((address_space(3))) u32*)&b_s[(i * 32 + wave * 8) * 64],
          16, 0, 0);
    }
    __syncthreads();
#pragma unroll
    for (int kk = 0; kk < 64; kk += 32) {
      const int kc = kk >> 3;
      bf16x8 af[4], bfr[4];
#pragma unroll
      for (int s = 0; s < 4; ++s) {
        int ra = wm + s * 16 + l15;
        int ph = (kc + q) ^ (ra & 7);
        af[s] = *(const bf16x8*)&a_s[ra * 64 + ph * 8];
      }
#pragma unroll
      for (int s = 0; s < 4; ++s) {
        int rb = wn + s * 16 + l15;
        int ph = (kc + q) ^ (rb & 7);
        bfr[s] = *(const bf16x8*)&b_s[rb * 64 + ph * 8];
      }
#pragma unroll
      for (int sm = 0; sm < 4; ++sm)
#pragma unroll
        for (int sn = 0; sn < 4; ++sn)
          acc[sm][sn] = __builtin_amdgcn_mfma_f32_16x16x32_bf16(af[sm], bfr[sn], acc[sm][sn], 0, 0, 0);
    }
    __syncthreads();
  }

  if (EPI == 0) {
    __shared__ __align__(16) f32x4 seg[256];
    // stash bf16 tile in LDS (stride 136 u16, 16B-aligned rows)
#pragma unroll
    for (int smi = 0; smi < 4; ++smi) {
#pragma unroll
      for (int r = 0; r < 4; ++r) {
        int lrow = wm + smi * 16 + q * 4 + r;
#pragma unroll
        for (int sni = 0; sni < 4; ++sni) {
          int lcol = wn + sni * 16 + l15;
          float v = acc[smi][sni][r] + bias4[sni];
          if (zlane) {
            float e = __expf(2.f * v);
            v = (e - 1.f) / (e + 1.f);
          }
          smem[lrow * 136 + lcol] = f2bf(v);
        }
      }
    }
    __syncthreads();
    // vectorized global stores: 8 x 16B per thread
#pragma unroll
    for (int it = 0; it < 8; ++it) {
      int flat = it * 256 + tid;
      int row = flat >> 4;
      int ch  = flat & 15;
      u16x8 vv = *(const u16x8*)&smem[row * 136 + ch * 8];
      *(u16x8*)(obf + (size_t)(bm + row) * N + bn + ch * 8) = vv;
    }
    // fused passA, split 2 threads per (ch,ck): 16 steps each, then compose
    {
      int unit = tid & 127;
      int half = tid >> 7;
      int ch = unit & 31, ck = unit >> 5;
      const u16* sp = smem + (ck * 32 + half * 16) * 136 + ch * 4;
      float F = 0.f, Mx = -1e30f, aBc = 0.f, aBn = 0.f;
#pragma unroll
      for (int t = 0; t < 16; ++t) {
        u16x4 gv = *(const u16x4*)(sp + t * 136);
        float i_t = b2f(gv[0]), f_t = b2f(gv[1]), z_t = b2f(gv[2]);
        float Mf = Mx + f_t;
        float Mn = fmaxf(Mf, i_t);
        float ea = __expf(Mf - Mn), eb = __expf(i_t - Mn);
        aBc = ea * aBc + eb * z_t;
        aBn = ea * aBn + eb;
        F += f_t; Mx = Mn;
      }
      seg[tid] = (f32x4){F, Mx, aBc, aBn};
    }
    __syncthreads();
    if (tid < 128) {
      f32x4 s0 = seg[tid], s1 = seg[tid + 128];
      float F = s0[0] + s1[0];
      float Mx = fmaxf(s0[1] + s1[0], s1[1]);
      float e0 = __expf(s0[1] + s1[0] - Mx), e1 = __expf(s1[1] - Mx);
      float aBc = e0 * s0[2] + e1 * s1[2];
      float aBn = e0 * s0[3] + e1 * s1[3];
      int ch = tid & 31, ck = tid >> 5;
      int b = bm >> 11;
      int s = ((bm & 2047) >> 5) + ck;
      int cg = (bn >> 2) + ch;
      sSum[(size_t)s * LANES_ + b * C_ + cg] = (f32x4){F, Mx, aBc, aBn};
    }
  } else {
    // two half-tiles through LDS as fp32 -> float4 resid add -> float4 stores
    float* fs = (float*)smem;
#pragma unroll
    for (int h = 0; h < 2; ++h) {
      __syncthreads();
#pragma unroll
      for (int smi2 = 0; smi2 < 2; ++smi2) {
        int smi = 2 * h + smi2;
#pragma unroll
        for (int r = 0; r < 4; ++r) {
          int slot = (wm >> 1) + smi2 * 16 + q * 4 + r;
#pragma unroll
          for (int sni = 0; sni < 4; ++sni) {
            int lcol = wn + sni * 16 + l15;
            fs[slot * 132 + lcol] = acc[smi][sni][r] + bias4[sni];
          }
        }
      }
      __syncthreads();
#pragma unroll
      for (int it = 0; it < 8; ++it) {
        int flat = it * 256 + tid;
        int slot = flat >> 5;
        int c4 = (flat & 31) * 4;
        int absrow = bm + ((slot & 32) << 1) + (h << 5) + (slot & 31);
        vf4 v = *(const vf4*)&fs[slot * 132 + c4];
        vf4 rv = *(const vf4*)(resid + (size_t)absrow * N + bn + c4);
        v[0] += rv[0]; v[1] += rv[1]; v[2] += rv[2]; v[3] += rv[3];
        *(vf4*)(of32 + (size_t)absrow * N + bn + c4) = v;
      }
    }
  }
}

// ---------------- fused scan: prefix + passB (h in regs) + GroupNorm, one dispatch ----------------
// 512 blocks x 256 threads, all co-resident (2 blocks/CU << capacity): spin barriers safe.
__global__ void scan_fused(const u16* __restrict__ gates, const f32x4* __restrict__ sSum,
                           f32x4* __restrict__ iSt, u16* __restrict__ hn,
                           const float* __restrict__ gn_w, const float* __restrict__ gn_b,
                           float* __restrict__ stats, int* __restrict__ flags) {
  const int tid = blockIdx.x * 256 + threadIdx.x;
  const int thr = threadIdx.x;

  // ---- phase 0: blocks 0..15 compute per-lane prefix over 64 chunk summaries ----
  if (blockIdx.x < 16) {
    int l = tid;                                // 0..4095
    float ct = 0.f, nt = 1.f, mt = 0.f;         // reference init (c=0, n=1, m=0)
#pragma unroll 8
    for (int s = 0; s < NCHUNK_; ++s) {
      int idx = s * LANES_ + l;
      f32x4 S = sSum[idx];
      iSt[idx] = (f32x4){ct, nt, mt, 0.f};
      float mf = mt + S[0];
      float mn = fmaxf(mf, S[1]);
      float a = __expf(mf - mn);
      float bcoef = __expf(S[1] - mn);
      ct = a * ct + bcoef * S[2];
      nt = a * nt + bcoef * S[3];
      mt = mn;
    }
    __syncthreads();                            // drains iSt stores (vmcnt)
    if (thr == 0)
      __hip_atomic_fetch_add(&flags[0], 1, __ATOMIC_RELEASE, __HIP_MEMORY_SCOPE_AGENT);
  }
  // ---- wait for prefix ----
  if (thr == 0) {
    while (__hip_atomic_load(&flags[0], __ATOMIC_ACQUIRE, __HIP_MEMORY_SCOPE_AGENT) < 16)
      __builtin_amdgcn_s_sleep(4);
  }
  __syncthreads();

  // ---- phase 1: passB exact replay, h kept in registers ----
  const int lp = tid & 2047;
  const int s = tid >> 11;
  const int b = lp >> 9;
  const int c2 = (lp & 511) * 2;
  const u16* g = gates + ((size_t)(b * T_ + s * CHUNK_) * C_ + c2) * 4;
  int idx = s * LANES_ + b * C_ + c2;
  f32x4 S0 = iSt[idx], S1 = iSt[idx + 1];
  float cc0 = S0[0], nn0 = S0[1], mm0 = S0[2];
  float cc1 = S1[0], nn1 = S1[1], mm1 = S1[2];
  float ls = 0.f, lq = 0.f;
  u32 hreg[CHUNK_];
#pragma unroll
  for (int t = 0; t < CHUNK_; ++t) {
    u16x8 gv = *(const u16x8*)(g + (size_t)t * C_ * 4);   // [i0 f0 z0 o0 i1 f1 z1 o1]
    float h0, h1;
    {
      float i_t = b2f(gv[0]), f_t = b2f(gv[1]), z_t = b2f(gv[2]), o_t = b2f(gv[3]);
      float m_new = fmaxf(f_t + mm0, i_t);
      float i_p = __expf(i_t - m_new);
      float f_p = __expf(f_t + mm0 - m_new);
      cc0 = f_p * cc0 + i_p * z_t;
      nn0 = f_p * nn0 + i_p;
      mm0 = m_new;
      float sig_o = 1.f / (1.f + __expf(-o_t));
      h0 = sig_o * (cc0 / (nn0 + 1e-6f));
    }
    {
      float i_t = b2f(gv[4]), f_t = b2f(gv[5]), z_t = b2f(gv[6]), o_t = b2f(gv[7]);
      float m_new = fmaxf(f_t + mm1, i_t);
      float i_p = __expf(i_t - m_new);
      float f_p = __expf(f_t + mm1 - m_new);
      cc1 = f_p * cc1 + i_p * z_t;
      nn1 = f_p * nn1 + i_p;
      mm1 = m_new;
      float sig_o = 1.f / (1.f + __expf(-o_t));
      h1 = sig_o * (cc1 / (nn1 + 1e-6f));
    }
    u16 hb0 = f2bf(h0), hb1 = f2bf(h1);
    float v0 = b2f(hb0), v1 = b2f(hb1);
    ls += v0 + v1; lq += v0 * v0 + v1 * v1;
    hreg[t] = (u32)hb0 | ((u32)hb1 << 16);
  }
  // block stats reduction (threads 0..127 and 128..255 are two distinct groups)
  __shared__ float rs[256], rq[256];
  rs[thr] = ls; rq[thr] = lq;
  __syncthreads();
  for (int off = 64; off > 0; off >>= 1) {
    if ((thr & 127) < off) { rs[thr] += rs[thr + off]; rq[thr] += rq[thr + off]; }
    __syncthreads();
  }
  const int grp = b * 4 + (c2 >> 8);
  if ((thr & 127) == 0) {
    atomicAdd(&stats[grp * 2 + 0], rs[thr]);
    atomicAdd(&stats[grp * 2 + 1], rq[thr]);
  }
  __syncthreads();                              // drains the stats atomics (vmcnt)
  if (thr == 0)
    __hip_atomic_fetch_add(&flags[1], 1, __ATOMIC_RELEASE, __HIP_MEMORY_SCOPE_AGENT);
  if (thr == 0) {
    while (__hip_atomic_load(&flags[1], __ATOMIC_ACQUIRE, __HIP_MEMORY_SCOPE_AGENT) < 512)
      __builtin_amdgcn_s_sleep(4);
  }
  __syncthreads();

  // ---- phase 2: normalize from registers, write hn ----
  const float inv_n = 1.f / (float)(T_ * D_);
  float mean = stats[grp * 2 + 0] * inv_n;
  float var  = stats[grp * 2 + 1] * inv_n - mean * mean;
  float rstd = rsqrtf(var + 1e-5f);
  float w_0 = gn_w[c2], w_1 = gn_w[c2 + 1];
  float bb0 = gn_b[c2], bb1 = gn_b[c2 + 1];
  u16* hp = hn + (size_t)(b * T_ + s * CHUNK_) * C_ + c2;
#pragma unroll
  for (int t = 0; t < CHUNK_; ++t) {
    u32 hv = hreg[t];
    float v0 = b2f((u16)hv), v1 = b2f((u16)(hv >> 16));
    u16 o0 = f2bf((v0 - mean) * rstd * w_0 + bb0);
    u16 o1 = f2bf((v1 - mean) * rstd * w_1 + bb1);
    *(u32*)(hp + (size_t)t * C_) = (u32)o0 | ((u32)o1 << 16);
  }
}

extern "C" void kernel_launch(void* const* d_in, const int* in_sizes, int n_in,
                              void* d_out, int out_size, void* d_ws, size_t ws_size,
                              hipStream_t stream) {
  const float* x      = (const float*)d_in[0];
  const float* conv_w = (const float*)d_in[1];
  const float* conv_b = (const float*)d_in[2];
  const float* wx_w   = (const float*)d_in[3];
  const float* wx_b   = (const float*)d_in[4];
  const float* gn_w   = (const float*)d_in[5];
  const float* gn_b   = (const float*)d_in[6];
  const float* out_w  = (const float*)d_in[7];
  const float* out_b  = (const float*)d_in[8];
  float* out = (float*)d_out;

  char* p = (char*)d_ws;
  u16* xc    = (u16*)p; p += (size_t)M_ * K_ * 2;      // 16.8 MB
  u16* w1    = (u16*)p; p += (size_t)N1_ * K_ * 2;     // 8.4 MB (permuted)
  u16* w2    = (u16*)p; p += (size_t)C_ * C_ * 2;      // 2.1 MB
  u16* gts   = (u16*)p; p += (size_t)M_ * N1_ * 2;     // 67.1 MB (interleaved c*4+g)
  u16* hn    = (u16*)p; p += (size_t)M_ * C_ * 2;      // 16.8 MB
  float* stats = (float*)p; p += 256;
  int* flags = (int*)p; p += 256;
  const int nsum = LANES_ * NCHUNK_;                   // 256K
  f32x4* sSum = (f32x4*)p; p += (size_t)nsum * 16;     // 4 MB
  f32x4* iSt  = (f32x4*)p; p += (size_t)nsum * 16;     // 4 MB

  // prologue: weight casts + conv/silu + zero stats/flags
  prep_kernel<<<NCAST_ + (M_ * C_) / 1024, 256, 0, stream>>>(
      wx_w, out_w, w1, w2, x, conv_w, conv_b, xc, stats, flags);

  // gates GEMM + fused passA (split-tail)
  gemm_bt<0><<<dim3(N1_ / 128, M_ / 128), 256, 0, stream>>>(
      xc, w1, wx_b, nullptr, gts, nullptr, sSum, M_, N1_, K_);

  // fused prefix + passB + GroupNorm
  scan_fused<<<512, 256, 0, stream>>>(gts, sSum, iSt, hn, gn_w, gn_b, stats, flags);

  // output GEMM + bias + residual
  gemm_bt<1><<<dim3(C_ / 128, M_ / 128), 256, 0, stream>>>(
      hn, w2, out_b, x, nullptr, out, nullptr, M_, C_, K_);
}

// Round 7
// 277.453 us; speedup vs baseline: 1.3753x; 1.3753x over previous
//
#include <hip/hip_runtime.h>

#define B_ 4
#define T_ 2048
#define C_ 1024
#define H_ 4
#define D_ 256
#define M_ (B_*T_)      /* 8192 */
#define N1_ (4*C_)      /* 4096 */
#define K_ C_           /* 1024 */
#define LANES_ (B_*C_)  /* 4096 */
#define CHUNK_ 32
#define NCHUNK_ (T_/CHUNK_)  /* 64 */

typedef unsigned short u16;
typedef unsigned int u32;
typedef __bf16 bf16x8 __attribute__((ext_vector_type(8)));
typedef float f32x4 __attribute__((ext_vector_type(4)));
typedef float vf4 __attribute__((ext_vector_type(4)));
typedef unsigned short u16x4 __attribute__((ext_vector_type(4)));
typedef unsigned short u16x8 __attribute__((ext_vector_type(8)));

__device__ __forceinline__ u16 f2bf(float f) {
  union { float f; u32 u; } v; v.f = f;
  u32 u = v.u;
  u32 r = (u + 0x7FFFu + ((u >> 16) & 1u)) >> 16;
  return (u16)r;
}
__device__ __forceinline__ float b2f(u16 h) {
  union { u32 u; float f; } v; v.u = ((u32)h) << 16;
  return v.f;
}

#define NCAST_ ((N1_*K_ + C_*C_) / 2048)   /* 2560 blocks for weight cast */

// ---------------- merged prologue: weight casts + conv+SiLU + zero stats ----------------
__global__ void prep_kernel(const float* __restrict__ wx_w, const float* __restrict__ out_w,
                            u16* __restrict__ w1p, u16* __restrict__ w2,
                            const float* __restrict__ x, const float* __restrict__ cw,
                            const float* __restrict__ cb, u16* __restrict__ xc,
                            float* __restrict__ stats) {
  if (blockIdx.x < NCAST_) {
    int i8 = (blockIdx.x * 256 + threadIdx.x) * 8;
    u16x8 o;
    if (i8 < N1_ * K_) {
      int n = i8 >> 10, k8 = i8 & 1023;
      const float* src = wx_w + (size_t)(((n & 3) << 10) | (n >> 2)) * K_ + k8;
      vf4 a = *(const vf4*)src;
      vf4 b = *(const vf4*)(src + 4);
#pragma unroll
      for (int j = 0; j < 4; ++j) { o[j] = f2bf(a[j]); o[j + 4] = f2bf(b[j]); }
      *(u16x8*)(w1p + i8) = o;
    } else {
      int j8 = i8 - N1_ * K_;
      vf4 a = *(const vf4*)(out_w + j8);
      vf4 b = *(const vf4*)(out_w + j8 + 4);
#pragma unroll
      for (int j = 0; j < 4; ++j) { o[j] = f2bf(a[j]); o[j + 4] = f2bf(b[j]); }
      *(u16x8*)(w2 + j8) = o;
    }
    return;
  }
  if (blockIdx.x == NCAST_ && threadIdx.x < 32) stats[threadIdx.x] = 0.f;
  int i4 = ((blockIdx.x - NCAST_) * 256 + threadIdx.x) * 4;
  int c = i4 & (C_ - 1);
  int t = (i4 >> 10) & (T_ - 1);
  vf4 acc = *(const vf4*)(cb + c);
  vf4 w0 = *(const vf4*)(cw + (size_t)c * 4);
  vf4 w1 = *(const vf4*)(cw + (size_t)(c + 1) * 4);
  vf4 w2v = *(const vf4*)(cw + (size_t)(c + 2) * 4);
  vf4 w3 = *(const vf4*)(cw + (size_t)(c + 3) * 4);
#pragma unroll
  for (int k = 0; k < 4; ++k) {
    if (t - 3 + k >= 0) {
      vf4 xv = *(const vf4*)(x + (size_t)i4 + (size_t)(k - 3) * C_);
      acc[0] = fmaf(w0[k], xv[0], acc[0]);
      acc[1] = fmaf(w1[k], xv[1], acc[1]);
      acc[2] = fmaf(w2v[k], xv[2], acc[2]);
      acc[3] = fmaf(w3[k], xv[3], acc[3]);
    }
  }
  u16x4 o;
#pragma unroll
  for (int j = 0; j < 4; ++j) {
    float s = acc[j] / (1.f + __expf(-acc[j]));
    o[j] = f2bf(s);
  }
  *(u16x4*)(xc + i4) = o;
}

// ---------------- bf16 MFMA GEMM, C[m][n] = sum_k A[m][k] * Bw[n][k] ----------------
template <int EPI>
__global__ __launch_bounds__(256, 3)
void gemm_bt(const u16* __restrict__ A, const u16* __restrict__ Bw,
             const float* __restrict__ bias, const float* __restrict__ resid,
             u16* __restrict__ obf, float* __restrict__ of32,
             f32x4* __restrict__ sSum, int M, int N, int K)
{
  __shared__ __align__(16) u16 smem[128 * 136];   // 34.8 KB; staging uses first 32 KB
  u16* a_s = smem;
  u16* b_s = smem + 128 * 64;

  const int tid  = threadIdx.x;
  const int lane = tid & 63;
  const int l15  = lane & 15;
  const int q    = lane >> 4;
  const int wave = tid >> 6;
  const int wm   = (wave >> 1) * 64;
  const int wn   = (wave & 1) * 64;
  const int bm   = blockIdx.y * 128;
  const int bn   = blockIdx.x * 128;

  const int srow   = wave * 8 + (lane >> 3);
  const int schunk = lane & 7;

  float bias4[4];
#pragma unroll
  for (int sn = 0; sn < 4; ++sn) {
    int gcol = bn + wn + sn * 16 + l15;
    bias4[sn] = (EPI == 0) ? bias[((gcol & 3) << 10) | (gcol >> 2)] : bias[gcol];
  }
  const bool zlane = (EPI == 0) && ((l15 & 3) == 2);

  f32x4 acc[4][4];
#pragma unroll
  for (int i = 0; i < 4; ++i)
#pragma unroll
    for (int j = 0; j < 4; ++j) acc[i][j] = (f32x4){0.f, 0.f, 0.f, 0.f};

  for (int k0 = 0; k0 < K; k0 += 64) {
#pragma unroll
    for (int i = 0; i < 4; ++i) {
      int r = i * 32 + srow;
      int lc = schunk ^ (r & 7);
      const u16* ga = A  + (size_t)(bm + r) * K + k0 + lc * 8;
      const u16* gb = Bw + (size_t)(bn + r) * K + k0 + lc * 8;
      __builtin_amdgcn_global_load_lds(
          (const __attribute__((address_space(1))) u32*)ga,
          (__attribute__((address_space(3))) u32*)&a_s[(i * 32 + wave * 8) * 64],
          16, 0, 0);
      __builtin_amdgcn_global_load_lds(
          (const __attribute__((address_space(1))) u32*)gb,
          (__attribute__((address_space(3))) u32*)&b_s[(i * 32 + wave * 8) * 64],
          16, 0, 0);
    }
    __syncthreads();
#pragma unroll
    for (int kk = 0; kk < 64; kk += 32) {
      const int kc = kk >> 3;
      bf16x8 af[4], bfr[4];
#pragma unroll
      for (int s = 0; s < 4; ++s) {
        int ra = wm + s * 16 + l15;
        int ph = (kc + q) ^ (ra & 7);
        af[s] = *(const bf16x8*)&a_s[ra * 64 + ph * 8];
      }
#pragma unroll
      for (int s = 0; s < 4; ++s) {
        int rb = wn + s * 16 + l15;
        int ph = (kc + q) ^ (rb & 7);
        bfr[s] = *(const bf16x8*)&b_s[rb * 64 + ph * 8];
      }
#pragma unroll
      for (int sm = 0; sm < 4; ++sm)
#pragma unroll
        for (int sn = 0; sn < 4; ++sn)
          acc[sm][sn] = __builtin_amdgcn_mfma_f32_16x16x32_bf16(af[sm], bfr[sn], acc[sm][sn], 0, 0, 0);
    }
    __syncthreads();
  }

  if (EPI == 0) {
    __shared__ __align__(16) f32x4 seg[256];
    // stash bf16 tile in LDS (stride 136 u16, 16B-aligned rows)
#pragma unroll
    for (int smi = 0; smi < 4; ++smi) {
#pragma unroll
      for (int r = 0; r < 4; ++r) {
        int lrow = wm + smi * 16 + q * 4 + r;
#pragma unroll
        for (int sni = 0; sni < 4; ++sni) {
          int lcol = wn + sni * 16 + l15;
          float v = acc[smi][sni][r] + bias4[sni];
          if (zlane) {
            float e = __expf(2.f * v);
            v = (e - 1.f) / (e + 1.f);
          }
          smem[lrow * 136 + lcol] = f2bf(v);
        }
      }
    }
    __syncthreads();
    // vectorized global stores: 8 x 16B per thread
#pragma unroll
    for (int it = 0; it < 8; ++it) {
      int flat = it * 256 + tid;
      int row = flat >> 4;
      int ch  = flat & 15;
      u16x8 vv = *(const u16x8*)&smem[row * 136 + ch * 8];
      *(u16x8*)(obf + (size_t)(bm + row) * N + bn + ch * 8) = vv;
    }
    // fused passA, split 2 threads per (ch,ck): 16 steps each, then compose
    {
      int unit = tid & 127;
      int half = tid >> 7;
      int ch = unit & 31, ck = unit >> 5;
      const u16* sp = smem + (ck * 32 + half * 16) * 136 + ch * 4;
      float F = 0.f, Mx = -1e30f, aBc = 0.f, aBn = 0.f;
#pragma unroll
      for (int t = 0; t < 16; ++t) {
        u16x4 gv = *(const u16x4*)(sp + t * 136);
        float i_t = b2f(gv[0]), f_t = b2f(gv[1]), z_t = b2f(gv[2]);
        float Mf = Mx + f_t;
        float Mn = fmaxf(Mf, i_t);
        float ea = __expf(Mf - Mn), eb = __expf(i_t - Mn);
        aBc = ea * aBc + eb * z_t;
        aBn = ea * aBn + eb;
        F += f_t; Mx = Mn;
      }
      seg[tid] = (f32x4){F, Mx, aBc, aBn};
    }
    __syncthreads();
    if (tid < 128) {
      f32x4 s0 = seg[tid], s1 = seg[tid + 128];
      float F = s0[0] + s1[0];
      float Mx = fmaxf(s0[1] + s1[0], s1[1]);
      float e0 = __expf(s0[1] + s1[0] - Mx), e1 = __expf(s1[1] - Mx);
      float aBc = e0 * s0[2] + e1 * s1[2];
      float aBn = e0 * s0[3] + e1 * s1[3];
      int ch = tid & 31, ck = tid >> 5;
      int b = bm >> 11;
      int s = ((bm & 2047) >> 5) + ck;
      int cg = (bn >> 2) + ch;
      sSum[(size_t)s * LANES_ + b * C_ + cg] = (f32x4){F, Mx, aBc, aBn};
    }
  } else {
    // two half-tiles through LDS as fp32 -> float4 resid add -> float4 stores
    float* fs = (float*)smem;
#pragma unroll
    for (int h = 0; h < 2; ++h) {
      __syncthreads();
#pragma unroll
      for (int smi2 = 0; smi2 < 2; ++smi2) {
        int smi = 2 * h + smi2;
#pragma unroll
        for (int r = 0; r < 4; ++r) {
          int slot = (wm >> 1) + smi2 * 16 + q * 4 + r;
#pragma unroll
          for (int sni = 0; sni < 4; ++sni) {
            int lcol = wn + sni * 16 + l15;
            fs[slot * 132 + lcol] = acc[smi][sni][r] + bias4[sni];
          }
        }
      }
      __syncthreads();
#pragma unroll
      for (int it = 0; it < 8; ++it) {
        int flat = it * 256 + tid;
        int slot = flat >> 5;
        int c4 = (flat & 31) * 4;
        int absrow = bm + ((slot & 32) << 1) + (h << 5) + (slot & 31);
        vf4 v = *(const vf4*)&fs[slot * 132 + c4];
        vf4 rv = *(const vf4*)(resid + (size_t)absrow * N + bn + c4);
        v[0] += rv[0]; v[1] += rv[1]; v[2] += rv[2]; v[3] += rv[3];
        *(vf4*)(of32 + (size_t)absrow * N + bn + c4) = v;
      }
    }
  }
}

// ---------------- scan: barrier-free local prefix + exact passB replay + GN stats ----------------
// sSum was written by the previous dispatch (gemm1) -> visible, no fences needed.
// Each block serves ONE chunk s; it locally folds chunks 0..s-1 for its own 512
// channels (same op sequence per lane as a global prefix -> bit-identical state).
__global__ void scan_local(const u16* __restrict__ gates, const f32x4* __restrict__ sSum,
                           u16* __restrict__ h, float* __restrict__ stats) {
  const int thr = threadIdx.x;
  const int tid = blockIdx.x * 256 + thr;
  const int lp = tid & 2047;
  const int s = tid >> 11;
  const int b = lp >> 9;
  const int c2 = (lp & 511) * 2;
  const int base = b * C_ + c2;

  // local prefix: fold chunk summaries 0..s-1 for channels c2, c2+1
  float cc0 = 0.f, nn0 = 1.f, mm0 = 0.f;
  float cc1 = 0.f, nn1 = 1.f, mm1 = 0.f;
  for (int j = 0; j < s; ++j) {
    f32x4 S0 = sSum[(size_t)j * LANES_ + base];
    f32x4 S1 = sSum[(size_t)j * LANES_ + base + 1];
    {
      float mf = mm0 + S0[0];
      float mn = fmaxf(mf, S0[1]);
      float a = __expf(mf - mn), bc = __expf(S0[1] - mn);
      cc0 = a * cc0 + bc * S0[2];
      nn0 = a * nn0 + bc * S0[3];
      mm0 = mn;
    }
    {
      float mf = mm1 + S1[0];
      float mn = fmaxf(mf, S1[1]);
      float a = __expf(mf - mn), bc = __expf(S1[1] - mn);
      cc1 = a * cc1 + bc * S1[2];
      nn1 = a * nn1 + bc * S1[3];
      mm1 = mn;
    }
  }

  // passB: exact reference replay over this chunk
  const u16* g = gates + ((size_t)(b * T_ + s * CHUNK_) * C_ + c2) * 4;
  u16* hp = h + (size_t)(b * T_ + s * CHUNK_) * C_ + c2;
  float ls = 0.f, lq = 0.f;
#pragma unroll 4
  for (int t = 0; t < CHUNK_; ++t) {
    u16x8 gv = *(const u16x8*)(g + (size_t)t * C_ * 4);   // [i0 f0 z0 o0 i1 f1 z1 o1]
    float h0, h1;
    {
      float i_t = b2f(gv[0]), f_t = b2f(gv[1]), z_t = b2f(gv[2]), o_t = b2f(gv[3]);
      float m_new = fmaxf(f_t + mm0, i_t);
      float i_p = __expf(i_t - m_new);
      float f_p = __expf(f_t + mm0 - m_new);
      cc0 = f_p * cc0 + i_p * z_t;
      nn0 = f_p * nn0 + i_p;
      mm0 = m_new;
      float sig_o = 1.f / (1.f + __expf(-o_t));
      h0 = sig_o * (cc0 / (nn0 + 1e-6f));
    }
    {
      float i_t = b2f(gv[4]), f_t = b2f(gv[5]), z_t = b2f(gv[6]), o_t = b2f(gv[7]);
      float m_new = fmaxf(f_t + mm1, i_t);
      float i_p = __expf(i_t - m_new);
      float f_p = __expf(f_t + mm1 - m_new);
      cc1 = f_p * cc1 + i_p * z_t;
      nn1 = f_p * nn1 + i_p;
      mm1 = m_new;
      float sig_o = 1.f / (1.f + __expf(-o_t));
      h1 = sig_o * (cc1 / (nn1 + 1e-6f));
    }
    u16 hb0 = f2bf(h0), hb1 = f2bf(h1);
    float v0 = b2f(hb0), v1 = b2f(hb1);
    ls += v0 + v1; lq += v0 * v0 + v1 * v1;
    *(u32*)(hp + (size_t)t * C_) = (u32)hb0 | ((u32)hb1 << 16);
  }
  // block stats reduction (threads 0..127 / 128..255 cover two distinct (b,h) groups)
  __shared__ float rs[256], rq[256];
  rs[thr] = ls; rq[thr] = lq;
  __syncthreads();
  for (int off = 64; off > 0; off >>= 1) {
    if ((thr & 127) < off) { rs[thr] += rs[thr + off]; rq[thr] += rq[thr + off]; }
    __syncthreads();
  }
  if ((thr & 127) == 0) {
    int grp = b * 4 + (c2 >> 8);
    atomicAdd(&stats[grp * 2 + 0], rs[thr]);
    atomicAdd(&stats[grp * 2 + 1], rq[thr]);
  }
}

// ---------------- apply GroupNorm -> bf16 hn (8 elems/thread) ----------------
__global__ void norm_kernel(const u16* __restrict__ h, const float* __restrict__ stats,
                            const float* __restrict__ gn_w, const float* __restrict__ gn_b,
                            u16* __restrict__ hn) {
  int i8 = (blockIdx.x * 256 + threadIdx.x) * 8;
  int c = i8 & (C_ - 1);
  int b = i8 >> 21;
  int grp = b * 4 + (c >> 8);
  const float inv_n = 1.f / (float)(T_ * D_);
  float mean = stats[grp * 2 + 0] * inv_n;
  float var  = stats[grp * 2 + 1] * inv_n - mean * mean;
  float rstd = rsqrtf(var + 1e-5f);
  u16x8 hv = *(const u16x8*)(h + i8);
  vf4 w0 = *(const vf4*)(gn_w + c), w1 = *(const vf4*)(gn_w + c + 4);
  vf4 b0 = *(const vf4*)(gn_b + c), b1 = *(const vf4*)(gn_b + c + 4);
  u16x8 o;
#pragma unroll
  for (int j = 0; j < 4; ++j) {
    o[j]     = f2bf((b2f(hv[j])     - mean) * rstd * w0[j] + b0[j]);
    o[j + 4] = f2bf((b2f(hv[j + 4]) - mean) * rstd * w1[j] + b1[j]);
  }
  *(u16x8*)(hn + i8) = o;
}

extern "C" void kernel_launch(void* const* d_in, const int* in_sizes, int n_in,
                              void* d_out, int out_size, void* d_ws, size_t ws_size,
                              hipStream_t stream) {
  const float* x      = (const float*)d_in[0];
  const float* conv_w = (const float*)d_in[1];
  const float* conv_b = (const float*)d_in[2];
  const float* wx_w   = (const float*)d_in[3];
  const float* wx_b   = (const float*)d_in[4];
  const float* gn_w   = (const float*)d_in[5];
  const float* gn_b   = (const float*)d_in[6];
  const float* out_w  = (const float*)d_in[7];
  const float* out_b  = (const float*)d_in[8];
  float* out = (float*)d_out;

  char* p = (char*)d_ws;
  u16* xc    = (u16*)p; p += (size_t)M_ * K_ * 2;      // 16.8 MB
  u16* w1    = (u16*)p; p += (size_t)N1_ * K_ * 2;     // 8.4 MB (permuted)
  u16* w2    = (u16*)p; p += (size_t)C_ * C_ * 2;      // 2.1 MB
  u16* gts   = (u16*)p; p += (size_t)M_ * N1_ * 2;     // 67.1 MB (interleaved c*4+g)
  u16* hb    = (u16*)p; p += (size_t)M_ * C_ * 2;      // 16.8 MB
  u16* hn    = (u16*)p; p += (size_t)M_ * C_ * 2;      // 16.8 MB
  float* stats = (float*)p; p += 256;
  const int nsum = LANES_ * NCHUNK_;                   // 256K
  f32x4* sSum = (f32x4*)p; p += (size_t)nsum * 16;     // 4 MB

  // prologue: weight casts + conv/silu + zero stats
  prep_kernel<<<NCAST_ + (M_ * C_) / 1024, 256, 0, stream>>>(
      wx_w, out_w, w1, w2, x, conv_w, conv_b, xc, stats);

  // gates GEMM + fused passA (split-tail)
  gemm_bt<0><<<dim3(N1_ / 128, M_ / 128), 256, 0, stream>>>(
      xc, w1, wx_b, nullptr, gts, nullptr, sSum, M_, N1_, K_);

  // barrier-free scan: local prefix + replay + stats
  scan_local<<<512, 256, 0, stream>>>(gts, sSum, hb, stats);

  // GroupNorm apply
  norm_kernel<<<(M_ * C_) / 2048, 256, 0, stream>>>(hb, stats, gn_w, gn_b, hn);

  // output GEMM + bias + residual
  gemm_bt<1><<<dim3(C_ / 128, M_ / 128), 256, 0, stream>>>(
      hn, w2, out_b, x, nullptr, out, nullptr, M_, C_, K_);
}